// Round 3
// baseline (436.047 us; speedup 1.0000x reference)
//
#include <hip/hip_runtime.h>

typedef unsigned short u16;
typedef __bf16 bf16x8 __attribute__((ext_vector_type(8)));
typedef float f32x4 __attribute__((ext_vector_type(4)));
typedef float f32x16 __attribute__((ext_vector_type(16)));

__device__ __forceinline__ u16 f2bf(float f) {
  union { float f; unsigned u; } v; v.f = f;
  unsigned r = (v.u + 0x7FFFu + ((v.u >> 16) & 1u)) >> 16;
  return (u16)r;
}
__device__ __forceinline__ float bf2f(u16 h) {
  union { unsigned u; float f; } v; v.u = ((unsigned)h) << 16;
  return v.f;
}

__device__ __forceinline__ void load_lds16(const void* g, void* l) {
  __builtin_amdgcn_global_load_lds((__attribute__((address_space(1))) void*)(g),
                                   (__attribute__((address_space(3))) void*)(l), 16, 0, 0);
}

// ---------------------------------------------------------------------------
// Small 128x128-tile bf16 GEMM body (16x16x32), used for QKV + merge.
// modes: 1 = elu(v)+1 fp32, 2 = v/1024 fp32, 3 = bf16 store
// ---------------------------------------------------------------------------
__device__ __forceinline__ void gemm128(
    const u16* __restrict__ A, const u16* __restrict__ Bt,
    float* __restrict__ Cf, u16* __restrict__ Cb,
    int N, int K, int mode,
    u16* lA, u16* lB)
{
  const int tid  = threadIdx.x;
  const int wave = tid >> 6;
  const int lane = tid & 63;
  const int wi = wave >> 1, wj = wave & 1;
  const int m0 = blockIdx.x * 128;
  const int n0 = blockIdx.y * 128;
  const int srow = lane >> 2;
  const int skc  = (lane & 3) * 8;
  const int lm = lane & 15;
  const int kq = (lane >> 4) * 8;

  f32x4 acc[4][4];
#pragma unroll
  for (int i = 0; i < 4; ++i)
#pragma unroll
    for (int j = 0; j < 4; ++j)
#pragma unroll
      for (int e = 0; e < 4; ++e) acc[i][j][e] = 0.f;

  const int kTiles = K >> 5;
  for (int kt = 0; kt < kTiles; ++kt) {
    __syncthreads();
#pragma unroll
    for (int t = 0; t < 2; ++t) {
      const int ci = wave * 2 + t;
      const u16* ga = A + (size_t)(m0 + ci * 16 + srow) * K + kt * 32 + skc;
      load_lds16(ga, &lA[ci * 512]);
      const u16* gb = Bt + (size_t)(n0 + ci * 16 + srow) * K + kt * 32 + skc;
      load_lds16(gb, &lB[ci * 512]);
    }
    asm volatile("s_waitcnt vmcnt(0)" ::: "memory");
    __syncthreads();
    bf16x8 af[4], bfr[4];
#pragma unroll
    for (int i = 0; i < 4; ++i)
      af[i] = *(const bf16x8*)&lA[(wi * 64 + i * 16 + lm) * 32 + kq];
#pragma unroll
    for (int j = 0; j < 4; ++j)
      bfr[j] = *(const bf16x8*)&lB[(wj * 64 + j * 16 + lm) * 32 + kq];
#pragma unroll
    for (int i = 0; i < 4; ++i)
#pragma unroll
      for (int j = 0; j < 4; ++j)
        acc[i][j] = __builtin_amdgcn_mfma_f32_16x16x32_bf16(af[i], bfr[j], acc[i][j], 0, 0, 0);
  }

  const int lq = lane >> 4;
#pragma unroll
  for (int i = 0; i < 4; ++i) {
#pragma unroll
    for (int j = 0; j < 4; ++j) {
      const int col  = n0 + wj * 64 + j * 16 + lm;
      const int row0 = m0 + wi * 64 + i * 16 + lq * 4;
#pragma unroll
      for (int r = 0; r < 4; ++r) {
        float v = acc[i][j][r];
        const size_t idx = (size_t)(row0 + r) * N + col;
        if (mode == 1)      Cf[idx] = (v > 0.f) ? (v + 1.f) : __expf(v);
        else if (mode == 2) Cf[idx] = v * (1.f / 1024.f);
        else                Cb[idx] = f2bf(v);
      }
    }
  }
}

// QKV: grid (32, 2, 3)
__global__ __launch_bounds__(256) void qkv_kernel(
    const u16* __restrict__ qbf, const u16* __restrict__ sbf,
    const u16* __restrict__ wqT, const u16* __restrict__ wkT, const u16* __restrict__ wvT,
    float* __restrict__ Qp, float* __restrict__ Kp, float* __restrict__ Vn)
{
  __shared__ __attribute__((aligned(16))) u16 lA[128 * 32];
  __shared__ __attribute__((aligned(16))) u16 lB[128 * 32];
  const int z = blockIdx.z;
  const u16* A = (z == 0) ? qbf : sbf;
  const u16* B = (z == 0) ? wqT : (z == 1) ? wkT : wvT;
  float* C = (z == 0) ? Qp : (z == 1) ? Kp : Vn;
  gemm128(A, B, C, nullptr, 256, 256, (z == 2) ? 2 : 1, lA, lB);
}

// merge: grid (32, 2)
__global__ __launch_bounds__(256) void merge_kernel(
    const u16* __restrict__ msg2, const u16* __restrict__ wmT, u16* __restrict__ merged)
{
  __shared__ __attribute__((aligned(16))) u16 lA[128 * 32];
  __shared__ __attribute__((aligned(16))) u16 lB[128 * 32];
  gemm128(msg2, wmT, nullptr, merged, 256, 256, 3, lA, lB);
}

// ---------------------------------------------------------------------------
// Fused MLP: per block, 64 pixels (one (b,i) row-half).
//  phase1: x NCHW -> LDS-transposed swizzled bf16 A-x (k 0..255)
//  4 chunks of 128 hidden cols:
//    GEMM1 (barrier-free): A from LDS (k<256) + global ub (k>=256), B=w1T global
//    hid chunk -> LDS (relu, bf16, swizzled)
//    GEMM2 partial: A=w2T global (m=channels), B=hid LDS (n=pixels) -> acc2 regs
//  LN stats in-register (col=pixel layout) + residual + NCHW store.
// grid: 1024 blocks. LDS = 32K + 16K + 2.5K -> 3 blocks/CU.
// ---------------------------------------------------------------------------
__global__ __launch_bounds__(256, 3) void mlp_fused_kernel(
    const float* __restrict__ x, const u16* __restrict__ ub,
    const u16* __restrict__ w1T, const u16* __restrict__ w2T,
    const float* __restrict__ g, const float* __restrict__ bb,
    float* __restrict__ out)
{
  __shared__ __attribute__((aligned(16))) u16 sAx[64 * 256];   // 32 KB
  __shared__ __attribute__((aligned(16))) u16 sH[64 * 128];    // 16 KB
  __shared__ __attribute__((aligned(16))) float sStat[640];    // 2.5 KB
  float* ts = (float*)sH;  // 64x33 fp32 alias (phase1 only)

  const int bx = blockIdx.x;
  const int b = bx >> 8, rem = bx & 255;
  const int i = rem >> 1, j0 = (rem & 1) * 64;
  const int pixbase = b * 16384 + i * 128 + j0;
  const int tid = threadIdx.x;
  const int w = tid >> 6, l = tid & 63;
  const int l31 = l & 31, hsel = l >> 5, h8 = hsel * 8;
  const int s7 = l31 & 7;

  // ---- phase 1: transpose x into sAx ----
  for (int cc = 0; cc < 4; ++cc) {
    for (int hh = 0; hh < 2; ++hh) {
      const int jj = tid & 31, cr = tid >> 5;
      const float* xp = x + ((size_t)(b * 256 + cc * 64 + cr) * 128 + i) * 128
                          + j0 + hh * 32 + jj;
#pragma unroll
      for (int it = 0; it < 8; ++it)
        ts[(it * 8 + cr) * 33 + jj] = xp[(size_t)it * 8 * 16384];
      __syncthreads();
      const int c = tid & 63, jr = tid >> 6;
      const int k = cc * 64 + c;
      const int kb = k >> 3, k7 = k & 7;
#pragma unroll
      for (int it = 0; it < 8; ++it) {
        const int jl = it * 4 + jr;
        const int px = hh * 32 + jl;
        sAx[px * 256 + ((kb ^ (px & 7)) << 3) + k7] = f2bf(ts[c * 33 + jl]);
      }
      __syncthreads();
    }
  }

  f32x16 acc2[4];
#pragma unroll
  for (int t = 0; t < 4; ++t)
#pragma unroll
    for (int e = 0; e < 16; ++e) acc2[t][e] = 0.f;

  const u16* ubp = ub + (size_t)pixbase * 256;
  const u16* up0 = ubp + (size_t)l31 * 256 + h8;
  const u16* up1 = ubp + (size_t)(32 + l31) * 256 + h8;
  const int hl = w * 32 + l31, hb = hl >> 3, h7 = hl & 7;

  for (int c4 = 0; c4 < 4; ++c4) {
    f32x16 acc1[2];
#pragma unroll
    for (int t = 0; t < 2; ++t)
#pragma unroll
      for (int e = 0; e < 16; ++e) acc1[t][e] = 0.f;

    const int n0 = c4 * 128 + w * 32;
    const u16* w1p = w1T + (size_t)(n0 + l31) * 512 + h8;

    // k-half 1: A from LDS
#pragma unroll 4
    for (int ki = 0; ki < 16; ++ki) {
      bf16x8 bf = *(const bf16x8*)(w1p + ki * 16);
      const int kb2 = ki * 2 + hsel;
      bf16x8 a0 = *(const bf16x8*)&sAx[l31 * 256 + ((kb2 ^ s7) << 3)];
      bf16x8 a1 = *(const bf16x8*)&sAx[(32 + l31) * 256 + ((kb2 ^ s7) << 3)];
      acc1[0] = __builtin_amdgcn_mfma_f32_32x32x16_bf16(a0, bf, acc1[0], 0, 0, 0);
      acc1[1] = __builtin_amdgcn_mfma_f32_32x32x16_bf16(a1, bf, acc1[1], 0, 0, 0);
    }
    // k-half 2: A from global ub
#pragma unroll 4
    for (int ki = 0; ki < 16; ++ki) {
      bf16x8 bf = *(const bf16x8*)(w1p + 256 + ki * 16);
      bf16x8 a0 = *(const bf16x8*)(up0 + ki * 16);
      bf16x8 a1 = *(const bf16x8*)(up1 + ki * 16);
      acc1[0] = __builtin_amdgcn_mfma_f32_32x32x16_bf16(a0, bf, acc1[0], 0, 0, 0);
      acc1[1] = __builtin_amdgcn_mfma_f32_32x32x16_bf16(a1, bf, acc1[1], 0, 0, 0);
    }

    // hid chunk -> LDS (relu, bf16)
#pragma unroll
    for (int mt = 0; mt < 2; ++mt)
#pragma unroll
      for (int r = 0; r < 16; ++r) {
        const int px = mt * 32 + (r & 3) + 8 * (r >> 2) + 4 * hsel;
        float v = acc1[mt][r];
        v = v > 0.f ? v : 0.f;
        sH[px * 128 + ((hb ^ (px & 7)) << 3) + h7] = f2bf(v);
      }
    __syncthreads();

    // GEMM2 partial
    const u16* w2p = w2T + (size_t)(w * 64 + l31) * 512 + c4 * 128 + h8;
#pragma unroll
    for (int ki = 0; ki < 8; ++ki) {
      bf16x8 af0 = *(const bf16x8*)(w2p + ki * 16);
      bf16x8 af1 = *(const bf16x8*)(w2p + (size_t)32 * 512 + ki * 16);
      const int hb2 = ki * 2 + hsel;
      bf16x8 b0 = *(const bf16x8*)&sH[l31 * 128 + ((hb2 ^ s7) << 3)];
      bf16x8 b1 = *(const bf16x8*)&sH[(32 + l31) * 128 + ((hb2 ^ s7) << 3)];
      acc2[0] = __builtin_amdgcn_mfma_f32_32x32x16_bf16(af0, b0, acc2[0], 0, 0, 0);
      acc2[1] = __builtin_amdgcn_mfma_f32_32x32x16_bf16(af0, b1, acc2[1], 0, 0, 0);
      acc2[2] = __builtin_amdgcn_mfma_f32_32x32x16_bf16(af1, b0, acc2[2], 0, 0, 0);
      acc2[3] = __builtin_amdgcn_mfma_f32_32x32x16_bf16(af1, b1, acc2[3], 0, 0, 0);
    }
    __syncthreads();
  }

  // ---- LN stats: per-pixel channel sums ----
  float s0 = 0.f, q0 = 0.f, s1 = 0.f, q1 = 0.f;
#pragma unroll
  for (int mi = 0; mi < 2; ++mi)
#pragma unroll
    for (int r = 0; r < 16; ++r) {
      const float v0 = acc2[mi * 2 + 0][r];
      const float v1 = acc2[mi * 2 + 1][r];
      s0 += v0; q0 += v0 * v0;
      s1 += v1; q1 += v1 * v1;
    }
  s0 += __shfl_xor(s0, 32, 64); q0 += __shfl_xor(q0, 32, 64);
  s1 += __shfl_xor(s1, 32, 64); q1 += __shfl_xor(q1, 32, 64);
  if (hsel == 0) {
    sStat[w * 64 + l31]            = s0;
    sStat[w * 64 + 32 + l31]       = s1;
    sStat[256 + w * 64 + l31]      = q0;
    sStat[256 + w * 64 + 32 + l31] = q1;
  }
  __syncthreads();
  if (tid < 64) {
    const float S = sStat[tid] + sStat[64 + tid] + sStat[128 + tid] + sStat[192 + tid];
    const float Q = sStat[256 + tid] + sStat[320 + tid] + sStat[384 + tid] + sStat[448 + tid];
    const float mean = S * (1.f / 256.f);
    const float var = Q * (1.f / 256.f) - mean * mean;
    sStat[512 + tid] = mean;
    sStat[576 + tid] = rsqrtf(var + 1e-5f);
  }
  __syncthreads();

  const float mu0 = sStat[512 + l31],      rs0 = sStat[576 + l31];
  const float mu1 = sStat[512 + 32 + l31], rs1 = sStat[576 + 32 + l31];

#pragma unroll
  for (int mi = 0; mi < 2; ++mi)
#pragma unroll
    for (int r = 0; r < 16; ++r) {
      const int ch = w * 64 + mi * 32 + (r & 3) + 8 * (r >> 2) + 4 * hsel;
      const float gg = g[ch], bv = bb[ch];
      const size_t base = ((size_t)(b * 256 + ch) * 128 + i) * 128 + j0;
      const float v0 = (acc2[mi * 2 + 0][r] - mu0) * rs0 * gg + bv;
      const float v1 = (acc2[mi * 2 + 1][r] - mu1) * rs1 * gg + bv;
      out[base + l31]      = x[base + l31] + v0;
      out[base + 32 + l31] = x[base + 32 + l31] + v1;
    }
}

// ---------------------------------------------------------------------------
// Weight transpose + bf16 cast: w[K][N] fp32 -> wt[N][K] bf16 (64x64 tiles)
// ---------------------------------------------------------------------------
__global__ __launch_bounds__(256) void transpose_w_kernel(
    const float* __restrict__ wq, const float* __restrict__ wk,
    const float* __restrict__ wv, const float* __restrict__ wm,
    const float* __restrict__ w1, const float* __restrict__ w2,
    u16* __restrict__ oq, u16* __restrict__ okk, u16* __restrict__ ov,
    u16* __restrict__ om, u16* __restrict__ o1, u16* __restrict__ o2)
{
  __shared__ float ts[64][65];
  int bid = blockIdx.x;
  const float* src; u16* dst; int K, N, t;
  if (bid < 64) {
    int wsel = bid >> 4; t = bid & 15; K = 256; N = 256;
    src = wsel == 0 ? wq : wsel == 1 ? wk : wsel == 2 ? wv : wm;
    dst = wsel == 0 ? oq : wsel == 1 ? okk : wsel == 2 ? ov : om;
  } else if (bid < 128) { t = bid - 64; K = 512; N = 512; src = w1; dst = o1; }
  else                  { t = bid - 128; K = 512; N = 256; src = w2; dst = o2; }
  const int ntn = N >> 6;
  const int tn = t % ntn, tk = t / ntn;
  const int tid = threadIdx.x, ln = tid & 63, lrr = tid >> 6;
  for (int k = 0; k < 64; k += 4)
    ts[k + lrr][ln] = src[(size_t)(tk * 64 + k + lrr) * N + tn * 64 + ln];
  __syncthreads();
  for (int k = 0; k < 64; k += 4)
    dst[(size_t)(tn * 64 + k + lrr) * K + tk * 64 + ln] = f2bf(ts[ln][k + lrr]);
}

// ---------------------------------------------------------------------------
// Fused 4x4 maxpool (NCHW) + layernorm over C -> bf16 rows
// ---------------------------------------------------------------------------
__global__ __launch_bounds__(256) void pool_ln_kernel(
    const float* __restrict__ x, const float* __restrict__ src,
    const float* __restrict__ g, const float* __restrict__ bb,
    u16* __restrict__ qout, u16* __restrict__ sout)
{
  __shared__ float pool[256 * 33];
  __shared__ float redA[8][32];
  __shared__ float redB[8][32];
  __shared__ float stat_m[32];
  __shared__ float stat_r[32];
  const int ph = blockIdx.x, b = blockIdx.y;
  const float* in = blockIdx.z ? src : x;
  u16* out = blockIdx.z ? sout : qout;
  const int tid = threadIdx.x;
  const int pw = tid & 31, cg = tid >> 5;
  for (int kk = 0; kk < 32; ++kk) {
    const int c = cg * 32 + kk;
    const float* base = in + (((size_t)b * 256 + c) * 128 + ph * 4) * 128 + pw * 4;
    float4 v0 = *(const float4*)(base);
    float4 v1 = *(const float4*)(base + 128);
    float4 v2 = *(const float4*)(base + 256);
    float4 v3 = *(const float4*)(base + 384);
    float m = fmaxf(fmaxf(fmaxf(v0.x, v0.y), fmaxf(v0.z, v0.w)),
                    fmaxf(fmaxf(v1.x, v1.y), fmaxf(v1.z, v1.w)));
    m = fmaxf(m, fmaxf(fmaxf(v2.x, v2.y), fmaxf(v2.z, v2.w)));
    m = fmaxf(m, fmaxf(fmaxf(v3.x, v3.y), fmaxf(v3.z, v3.w)));
    pool[c * 33 + pw] = m;
  }
  __syncthreads();
  float s = 0.f, s2 = 0.f;
  for (int i = 0; i < 32; ++i) {
    float v = pool[(cg * 32 + i) * 33 + pw];
    s += v; s2 += v * v;
  }
  redA[cg][pw] = s; redB[cg][pw] = s2;
  __syncthreads();
  if (tid < 32) {
    float ss = 0.f, ss2 = 0.f;
    for (int i = 0; i < 8; ++i) { ss += redA[i][tid]; ss2 += redB[i][tid]; }
    float mean = ss * (1.f / 256.f);
    float var = ss2 * (1.f / 256.f) - mean * mean;
    stat_m[tid] = mean;
    stat_r[tid] = rsqrtf(var + 1e-5f);
  }
  __syncthreads();
  const float gc = g[tid], bc = bb[tid];
  const size_t rowbase = ((size_t)b * 1024 + ph * 32) * 256;
  for (int p = 0; p < 32; ++p) {
    float v = (pool[tid * 33 + p] - stat_m[p]) * stat_r[p] * gc + bc;
    out[rowbase + (size_t)p * 256 + tid] = f2bf(v);
  }
}

// ---------------------------------------------------------------------------
// KV[d][v] + Ksum[d] per (b,h). grid (8 h, 4 b)
// ---------------------------------------------------------------------------
__global__ __launch_bounds__(256) void kv_kernel(
    const float* __restrict__ Kp, const float* __restrict__ Vn,
    float* __restrict__ kvbuf)
{
  __shared__ float kch[128 * 33];
  __shared__ float vch[128 * 33];
  const int h = blockIdx.x, b = blockIdx.y;
  const int tid = threadIdx.x;
  const int d = tid & 31, sl = tid >> 5;
  const int v = tid & 31, dp = tid >> 5;
  float a0 = 0.f, a1 = 0.f, a2 = 0.f, a3 = 0.f, ks = 0.f;
  for (int ch = 0; ch < 8; ++ch) {
    __syncthreads();
    for (int ss = 0; ss < 16; ++ss) {
      const int srow = ch * 128 + ss * 8 + sl;
      const size_t gi = ((size_t)b * 1024 + srow) * 256 + h * 32 + d;
      kch[(ss * 8 + sl) * 33 + d] = Kp[gi];
      vch[(ss * 8 + sl) * 33 + d] = Vn[gi];
    }
    __syncthreads();
    for (int s = 0; s < 128; ++s) {
      const float vv = vch[s * 33 + v];
      a0 += kch[s * 33 + dp] * vv;
      a1 += kch[s * 33 + dp + 8] * vv;
      a2 += kch[s * 33 + dp + 16] * vv;
      a3 += kch[s * 33 + dp + 24] * vv;
    }
    if (tid < 32)
      for (int s = 0; s < 128; ++s) ks += kch[s * 33 + tid];
  }
  float* outp = kvbuf + ((size_t)b * 8 + h) * 1056;
  outp[(dp) * 32 + v]      = a0;
  outp[(dp + 8) * 32 + v]  = a1;
  outp[(dp + 16) * 32 + v] = a2;
  outp[(dp + 24) * 32 + v] = a3;
  if (tid < 32) outp[1024 + tid] = ks;
}

// ---------------------------------------------------------------------------
// msg[l,h,v] = (Qp[l].KV[:,v]) * 1024 / (Qp[l].Ksum + 1e-6) -> bf16
// ---------------------------------------------------------------------------
__global__ __launch_bounds__(256) void msg_kernel(
    const float* __restrict__ Qp, const float* __restrict__ kvbuf,
    u16* __restrict__ msg2)
{
  __shared__ float kv[32 * 33];
  __shared__ float ksum[32];
  __shared__ float qch[8 * 33];
  const int lc = blockIdx.x, h = blockIdx.y, b = blockIdx.z;
  const int tid = threadIdx.x;
  const float* kvp = kvbuf + ((size_t)b * 8 + h) * 1056;
  for (int i = tid; i < 1024; i += 256) kv[(i >> 5) * 33 + (i & 31)] = kvp[i];
  if (tid < 32) ksum[tid] = kvp[1024 + tid];
  const int d = tid & 31, lr = tid >> 5;
  const int v = tid & 31;
  for (int ps = 0; ps < 8; ++ps) {
    __syncthreads();
    const int l = lc * 64 + ps * 8 + lr;
    qch[lr * 33 + d] = Qp[((size_t)b * 1024 + l) * 256 + h * 32 + d];
    __syncthreads();
    float dot = 0.f, zden = 0.f;
    for (int dd = 0; dd < 32; ++dd) {
      const float q = qch[lr * 33 + dd];
      dot  += q * kv[dd * 33 + v];
      zden += q * ksum[dd];
    }
    const float m = dot * (1024.f / (zden + 1e-6f));
    msg2[((size_t)b * 1024 + l) * 256 + h * 32 + v] = f2bf(m);
  }
}

// ---------------------------------------------------------------------------
// Upsample-only prep: bilinear 4x of merged -> ub[pix][256] bf16
// grid (2 jc, 512), block 256 (c = tid)
// ---------------------------------------------------------------------------
__global__ __launch_bounds__(256) void up_kernel(
    const u16* __restrict__ merged, u16* __restrict__ ub)
{
  const int jc = blockIdx.x, iz = blockIdx.y;
  const int b = iz >> 7;
  const int i = iz & 127;
  const int tid = threadIdx.x;
  const float sy = 0.25f * i - 0.375f;
  const float fy = floorf(sy);
  const float wy = sy - fy;
  const int y0 = max(0, min(31, (int)fy));
  const int y1 = max(0, min(31, (int)fy + 1));
  const u16* mb = merged + (size_t)b * 1024 * 256;
  for (int p = 0; p < 64; ++p) {
    const int j = jc * 64 + p;
    const float sx = 0.25f * j - 0.375f;
    const float fx = floorf(sx);
    const float wx = sx - fx;
    const int x0 = max(0, min(31, (int)fx));
    const int x1 = max(0, min(31, (int)fx + 1));
    const u16* r00 = mb + ((size_t)y0 * 32 + x0) * 256;
    const u16* r01 = mb + ((size_t)y0 * 32 + x1) * 256;
    const u16* r10 = mb + ((size_t)y1 * 32 + x0) * 256;
    const u16* r11 = mb + ((size_t)y1 * 32 + x1) * 256;
    const float v = (1.f - wy) * ((1.f - wx) * bf2f(r00[tid]) + wx * bf2f(r01[tid]))
                  +        wy  * ((1.f - wx) * bf2f(r10[tid]) + wx * bf2f(r11[tid]));
    const size_t row = (size_t)b * 16384 + (size_t)i * 128 + j;
    ub[row * 256 + tid] = f2bf(v);
  }
}

// ---------------------------------------------------------------------------
extern "C" void kernel_launch(void* const* d_in, const int* in_sizes, int n_in,
                              void* d_out, int out_size, void* d_ws, size_t ws_size,
                              hipStream_t stream) {
  (void)in_sizes; (void)n_in; (void)out_size; (void)ws_size;
  const float* x   = (const float*)d_in[0];
  const float* src = (const float*)d_in[1];
  const float* n1g = (const float*)d_in[2];
  const float* n1b = (const float*)d_in[3];
  const float* w_q = (const float*)d_in[4];
  const float* w_k = (const float*)d_in[5];
  const float* w_v = (const float*)d_in[6];
  const float* w_m = (const float*)d_in[7];
  const float* w1  = (const float*)d_in[8];
  const float* w2  = (const float*)d_in[9];
  const float* n2g = (const float*)d_in[10];
  const float* n2b = (const float*)d_in[11];
  float* out = (float*)d_out;

  char* ws = (char*)d_ws;
  size_t off = 0;
  auto alloc = [&](size_t bytes) -> void* {
    void* p = ws + off;
    off = (off + bytes + 255) & ~(size_t)255;
    return p;
  };
  u16* wqT = (u16*)alloc(256 * 256 * 2);
  u16* wkT = (u16*)alloc(256 * 256 * 2);
  u16* wvT = (u16*)alloc(256 * 256 * 2);
  u16* wmT = (u16*)alloc(256 * 256 * 2);
  u16* w1T = (u16*)alloc(512 * 512 * 2);
  u16* w2T = (u16*)alloc(256 * 512 * 2);
  u16* qbf = (u16*)alloc((size_t)4096 * 256 * 2);
  u16* sbf = (u16*)alloc((size_t)4096 * 256 * 2);
  float* Qp = (float*)alloc((size_t)4096 * 256 * 4);
  float* Kp = (float*)alloc((size_t)4096 * 256 * 4);
  float* Vn = (float*)alloc((size_t)4096 * 256 * 4);
  float* kvb = (float*)alloc((size_t)32 * 1056 * 4);
  u16* msg2   = (u16*)alloc((size_t)4096 * 256 * 2);
  u16* merged = (u16*)alloc((size_t)4096 * 256 * 2);
  u16* ub     = (u16*)alloc((size_t)65536 * 256 * 2);

  transpose_w_kernel<<<dim3(160), dim3(256), 0, stream>>>(
      w_q, w_k, w_v, w_m, w1, w2, wqT, wkT, wvT, wmT, w1T, w2T);

  pool_ln_kernel<<<dim3(32, 4, 2), dim3(256), 0, stream>>>(
      x, src, n1g, n1b, qbf, sbf);

  qkv_kernel<<<dim3(32, 2, 3), dim3(256), 0, stream>>>(
      qbf, sbf, wqT, wkT, wvT, Qp, Kp, Vn);

  kv_kernel<<<dim3(8, 4), dim3(256), 0, stream>>>(Kp, Vn, kvb);
  msg_kernel<<<dim3(16, 8, 4), dim3(256), 0, stream>>>(Qp, kvb, msg2);

  merge_kernel<<<dim3(32, 2), dim3(256), 0, stream>>>(msg2, wmT, merged);

  up_kernel<<<dim3(2, 512), dim3(256), 0, stream>>>(merged, ub);

  mlp_fused_kernel<<<dim3(1024), dim3(256), 0, stream>>>(
      x, ub, w1T, w2T, n2g, n2b, out);
}

// Round 4
// 365.204 us; speedup vs baseline: 1.1940x; 1.1940x over previous
//
#include <hip/hip_runtime.h>

typedef unsigned short u16;
typedef __bf16 bf16x8 __attribute__((ext_vector_type(8)));
typedef float f32x4 __attribute__((ext_vector_type(4)));
typedef float f32x16 __attribute__((ext_vector_type(16)));

__device__ __forceinline__ u16 f2bf(float f) {
  union { float f; unsigned u; } v; v.f = f;
  unsigned r = (v.u + 0x7FFFu + ((v.u >> 16) & 1u)) >> 16;
  return (u16)r;
}
__device__ __forceinline__ float bf2f(u16 h) {
  union { unsigned u; float f; } v; v.u = ((unsigned)h) << 16;
  return v.f;
}

__device__ __forceinline__ void load_lds16(const void* g, void* l) {
  __builtin_amdgcn_global_load_lds((__attribute__((address_space(1))) void*)(g),
                                   (__attribute__((address_space(3))) void*)(l), 16, 0, 0);
}

// ---------------------------------------------------------------------------
// Small 128x128-tile bf16 GEMM body (16x16x32), used for QKV + merge.
// modes: 1 = elu(v)+1 fp32, 2 = v/1024 fp32, 3 = bf16 store
// ---------------------------------------------------------------------------
__device__ __forceinline__ void gemm128(
    const u16* __restrict__ A, const u16* __restrict__ Bt,
    float* __restrict__ Cf, u16* __restrict__ Cb,
    int N, int K, int mode,
    u16* lA, u16* lB)
{
  const int tid  = threadIdx.x;
  const int wave = tid >> 6;
  const int lane = tid & 63;
  const int wi = wave >> 1, wj = wave & 1;
  const int m0 = blockIdx.x * 128;
  const int n0 = blockIdx.y * 128;
  const int srow = lane >> 2;
  const int skc  = (lane & 3) * 8;
  const int lm = lane & 15;
  const int kq = (lane >> 4) * 8;

  f32x4 acc[4][4];
#pragma unroll
  for (int i = 0; i < 4; ++i)
#pragma unroll
    for (int j = 0; j < 4; ++j)
#pragma unroll
      for (int e = 0; e < 4; ++e) acc[i][j][e] = 0.f;

  const int kTiles = K >> 5;
  for (int kt = 0; kt < kTiles; ++kt) {
    __syncthreads();
#pragma unroll
    for (int t = 0; t < 2; ++t) {
      const int ci = wave * 2 + t;
      const u16* ga = A + (size_t)(m0 + ci * 16 + srow) * K + kt * 32 + skc;
      load_lds16(ga, &lA[ci * 512]);
      const u16* gb = Bt + (size_t)(n0 + ci * 16 + srow) * K + kt * 32 + skc;
      load_lds16(gb, &lB[ci * 512]);
    }
    asm volatile("s_waitcnt vmcnt(0)" ::: "memory");
    __syncthreads();
    bf16x8 af[4], bfr[4];
#pragma unroll
    for (int i = 0; i < 4; ++i)
      af[i] = *(const bf16x8*)&lA[(wi * 64 + i * 16 + lm) * 32 + kq];
#pragma unroll
    for (int j = 0; j < 4; ++j)
      bfr[j] = *(const bf16x8*)&lB[(wj * 64 + j * 16 + lm) * 32 + kq];
#pragma unroll
    for (int i = 0; i < 4; ++i)
#pragma unroll
      for (int j = 0; j < 4; ++j)
        acc[i][j] = __builtin_amdgcn_mfma_f32_16x16x32_bf16(af[i], bfr[j], acc[i][j], 0, 0, 0);
  }

  const int lq = lane >> 4;
#pragma unroll
  for (int i = 0; i < 4; ++i) {
#pragma unroll
    for (int j = 0; j < 4; ++j) {
      const int col  = n0 + wj * 64 + j * 16 + lm;
      const int row0 = m0 + wi * 64 + i * 16 + lq * 4;
#pragma unroll
      for (int r = 0; r < 4; ++r) {
        float v = acc[i][j][r];
        const size_t idx = (size_t)(row0 + r) * N + col;
        if (mode == 1)      Cf[idx] = (v > 0.f) ? (v + 1.f) : __expf(v);
        else if (mode == 2) Cf[idx] = v * (1.f / 1024.f);
        else                Cb[idx] = f2bf(v);
      }
    }
  }
}

// QKV: grid (32, 2, 3)
__global__ __launch_bounds__(256) void qkv_kernel(
    const u16* __restrict__ qbf, const u16* __restrict__ sbf,
    const u16* __restrict__ wqT, const u16* __restrict__ wkT, const u16* __restrict__ wvT,
    float* __restrict__ Qp, float* __restrict__ Kp, float* __restrict__ Vn)
{
  __shared__ __attribute__((aligned(16))) u16 lA[128 * 32];
  __shared__ __attribute__((aligned(16))) u16 lB[128 * 32];
  const int z = blockIdx.z;
  const u16* A = (z == 0) ? qbf : sbf;
  const u16* B = (z == 0) ? wqT : (z == 1) ? wkT : wvT;
  float* C = (z == 0) ? Qp : (z == 1) ? Kp : Vn;
  gemm128(A, B, C, nullptr, 256, 256, (z == 2) ? 2 : 1, lA, lB);
}

// merge: grid (32, 2)
__global__ __launch_bounds__(256) void merge_kernel(
    const u16* __restrict__ msg2, const u16* __restrict__ wmT, u16* __restrict__ merged)
{
  __shared__ __attribute__((aligned(16))) u16 lA[128 * 32];
  __shared__ __attribute__((aligned(16))) u16 lB[128 * 32];
  gemm128(msg2, wmT, nullptr, merged, 256, 256, 3, lA, lB);
}

// ---------------------------------------------------------------------------
// MLP1: hid[r][n] = relu(cat(xbf,ub)[r] . w1T[n]),  r: 128-rows/blk, n: 256/blk
// 32x32x16 MFMA, BK=64, XOR-swizzled LDS, grid (2, Mrows/128)
// ---------------------------------------------------------------------------
__global__ __launch_bounds__(256, 2) void mlp1_kernel(
    const u16* __restrict__ xbf, const u16* __restrict__ ub,
    const u16* __restrict__ w1T, u16* __restrict__ hid)
{
  __shared__ __attribute__((aligned(16))) u16 lA[128 * 64];  // 16 KB
  __shared__ __attribute__((aligned(16))) u16 lB[256 * 64];  // 32 KB
  const int tid = threadIdx.x;
  const int w = tid >> 6, l = tid & 63;
  const int wi = w >> 1, wj = w & 1;
  const int n0 = blockIdx.x * 256;
  const int m0 = blockIdx.y * 128;
  const int sr8 = l >> 3;          // row-within-8 for staging
  const int kbg = (l & 7) ^ sr8;   // swizzled global k-block

  f32x16 acc[2][4];
#pragma unroll
  for (int ti = 0; ti < 2; ++ti)
#pragma unroll
    for (int tj = 0; tj < 4; ++tj)
#pragma unroll
      for (int e = 0; e < 16; ++e) acc[ti][tj][e] = 0.f;

  for (int kc = 0; kc < 8; ++kc) {
    const u16* Asrc = (kc < 4) ? (xbf + kc * 64) : (ub + (kc - 4) * 64);
    __syncthreads();
#pragma unroll
    for (int it = 0; it < 4; ++it) {
      const int r = it * 32 + w * 8 + sr8;
      load_lds16(Asrc + (size_t)(m0 + r) * 256 + kbg * 8, &lA[(it * 32 + w * 8) * 64]);
    }
#pragma unroll
    for (int it = 0; it < 8; ++it) {
      const int r = it * 32 + w * 8 + sr8;
      load_lds16(w1T + (size_t)(n0 + r) * 512 + kc * 64 + kbg * 8, &lB[(it * 32 + w * 8) * 64]);
    }
    asm volatile("s_waitcnt vmcnt(0)" ::: "memory");
    __syncthreads();
    const int h = l >> 5;
#pragma unroll
    for (int s = 0; s < 4; ++s) {
      const int kb = s * 2 + h;
      bf16x8 af[2], bfr[4];
#pragma unroll
      for (int ti = 0; ti < 2; ++ti) {
        const int rt = wi * 64 + ti * 32 + (l & 31);
        af[ti] = *(const bf16x8*)&lA[rt * 64 + (kb ^ (rt & 7)) * 8];
      }
#pragma unroll
      for (int tj = 0; tj < 4; ++tj) {
        const int rn = wj * 128 + tj * 32 + (l & 31);
        bfr[tj] = *(const bf16x8*)&lB[rn * 64 + (kb ^ (rn & 7)) * 8];
      }
#pragma unroll
      for (int ti = 0; ti < 2; ++ti)
#pragma unroll
        for (int tj = 0; tj < 4; ++tj)
          acc[ti][tj] = __builtin_amdgcn_mfma_f32_32x32x16_bf16(af[ti], bfr[tj], acc[ti][tj], 0, 0, 0);
    }
  }

  const int h = l >> 5;
#pragma unroll
  for (int ti = 0; ti < 2; ++ti)
#pragma unroll
    for (int tj = 0; tj < 4; ++tj)
#pragma unroll
      for (int rg = 0; rg < 16; ++rg) {
        const int row = m0 + wi * 64 + ti * 32 + (rg & 3) + 8 * (rg >> 2) + 4 * h;
        const int col = n0 + wj * 128 + tj * 32 + (l & 31);
        const float v = acc[ti][tj][rg];
        hid[(size_t)row * 512 + col] = f2bf(v > 0.f ? v : 0.f);
      }
}

// ---------------------------------------------------------------------------
// MLP2 v2: A = w2T (256 channels), B = hid (128 pixels/block), K = 512.
// C layout: channel on regs, pixel on lanes -> LN stats in-register.
// Fused LN + residual + NCHW store. grid (rows/128). LDS 48 KB.
// ---------------------------------------------------------------------------
__global__ __launch_bounds__(256, 2) void mlp2_kernel(
    const u16* __restrict__ hid, const u16* __restrict__ w2T,
    const float* __restrict__ x, const float* __restrict__ g,
    const float* __restrict__ bb, float* __restrict__ out, int pixbase)
{
  __shared__ __attribute__((aligned(16))) u16 lA[256 * 64];  // 32 KB (w2T chunk)
  __shared__ __attribute__((aligned(16))) u16 lB[128 * 64];  // 16 KB (hid chunk)
  float* sb = (float*)lB;  // alias after K-loop: [0..511] S, [512..1023] Q,
                           // [1024..1151] mu, [1152..1279] rs

  const int tid = threadIdx.x;
  const int w = tid >> 6, l = tid & 63;
  const int l31 = l & 31, hsel = l >> 5;
  const int s7 = l31 & 7;
  const int m0 = blockIdx.x * 128;          // local pixel base
  const int sr8 = l >> 3;
  const int kbg = (l & 7) ^ sr8;

  f32x16 acc[2][4];
#pragma unroll
  for (int mi = 0; mi < 2; ++mi)
#pragma unroll
    for (int nj = 0; nj < 4; ++nj)
#pragma unroll
      for (int e = 0; e < 16; ++e) acc[mi][nj][e] = 0.f;

  for (int kc = 0; kc < 8; ++kc) {
    __syncthreads();
#pragma unroll
    for (int it = 0; it < 8; ++it) {
      const int r = it * 32 + w * 8 + sr8;
      load_lds16(w2T + (size_t)r * 512 + kc * 64 + kbg * 8, &lA[(it * 32 + w * 8) * 64]);
    }
#pragma unroll
    for (int it = 0; it < 4; ++it) {
      const int r = it * 32 + w * 8 + sr8;
      load_lds16(hid + (size_t)(m0 + r) * 512 + kc * 64 + kbg * 8, &lB[(it * 32 + w * 8) * 64]);
    }
    asm volatile("s_waitcnt vmcnt(0)" ::: "memory");
    __syncthreads();
#pragma unroll
    for (int s = 0; s < 4; ++s) {
      const int kb = s * 2 + hsel;
      bf16x8 af[2], bf[4];
#pragma unroll
      for (int mi = 0; mi < 2; ++mi) {
        const int rt = w * 64 + mi * 32 + l31;
        af[mi] = *(const bf16x8*)&lA[rt * 64 + ((kb ^ s7) << 3)];
      }
#pragma unroll
      for (int nj = 0; nj < 4; ++nj) {
        const int rn = nj * 32 + l31;
        bf[nj] = *(const bf16x8*)&lB[rn * 64 + ((kb ^ s7) << 3)];
      }
#pragma unroll
      for (int mi = 0; mi < 2; ++mi)
#pragma unroll
        for (int nj = 0; nj < 4; ++nj)
          acc[mi][nj] = __builtin_amdgcn_mfma_f32_32x32x16_bf16(af[mi], bf[nj], acc[mi][nj], 0, 0, 0);
    }
  }

  // ---- LN stats: per-pixel (lane) channel sums, in-register ----
  float S[4], Q[4];
#pragma unroll
  for (int nj = 0; nj < 4; ++nj) {
    float s = 0.f, q = 0.f;
#pragma unroll
    for (int mi = 0; mi < 2; ++mi)
#pragma unroll
      for (int rg = 0; rg < 16; ++rg) {
        const float v = acc[mi][nj][rg];
        s += v; q += v * v;
      }
    s += __shfl_xor(s, 32, 64);
    q += __shfl_xor(q, 32, 64);
    S[nj] = s; Q[nj] = q;
  }
  __syncthreads();   // all waves done reading lB; safe to alias
  if (hsel == 0) {
#pragma unroll
    for (int nj = 0; nj < 4; ++nj) {
      sb[w * 128 + nj * 32 + l31]       = S[nj];
      sb[512 + w * 128 + nj * 32 + l31] = Q[nj];
    }
  }
  __syncthreads();
  if (tid < 128) {
    const float Sf = sb[tid] + sb[128 + tid] + sb[256 + tid] + sb[384 + tid];
    const float Qf = sb[512 + tid] + sb[640 + tid] + sb[768 + tid] + sb[896 + tid];
    const float mean = Sf * (1.f / 256.f);
    const float var = Qf * (1.f / 256.f) - mean * mean;
    sb[1024 + tid] = mean;
    sb[1152 + tid] = rsqrtf(var + 1e-5f);
  }
  __syncthreads();

  float mu[4], rs[4];
#pragma unroll
  for (int nj = 0; nj < 4; ++nj) {
    mu[nj] = sb[1024 + nj * 32 + l31];
    rs[nj] = sb[1152 + nj * 32 + l31];
  }

  const int gp = pixbase + m0;
  const int b = gp >> 14;
  const int i = (gp & 16383) >> 7;

#pragma unroll
  for (int mi = 0; mi < 2; ++mi)
#pragma unroll
    for (int rg = 0; rg < 16; ++rg) {
      const int ch = w * 64 + mi * 32 + (rg & 3) + 8 * (rg >> 2) + 4 * hsel;
      const float gg = g[ch], bv = bb[ch];
      const size_t base = ((size_t)(b * 256 + ch) * 128 + i) * 128;
#pragma unroll
      for (int nj = 0; nj < 4; ++nj) {
        const int p = nj * 32 + l31;
        const float v = (acc[mi][nj][rg] - mu[nj]) * rs[nj] * gg + bv;
        out[base + p] = x[base + p] + v;
      }
    }
}

// ---------------------------------------------------------------------------
// Weight transpose + bf16 cast: w[K][N] fp32 -> wt[N][K] bf16 (64x64 tiles)
// ---------------------------------------------------------------------------
__global__ __launch_bounds__(256) void transpose_w_kernel(
    const float* __restrict__ wq, const float* __restrict__ wk,
    const float* __restrict__ wv, const float* __restrict__ wm,
    const float* __restrict__ w1, const float* __restrict__ w2,
    u16* __restrict__ oq, u16* __restrict__ okk, u16* __restrict__ ov,
    u16* __restrict__ om, u16* __restrict__ o1, u16* __restrict__ o2)
{
  __shared__ float ts[64][65];
  int bid = blockIdx.x;
  const float* src; u16* dst; int K, N, t;
  if (bid < 64) {
    int wsel = bid >> 4; t = bid & 15; K = 256; N = 256;
    src = wsel == 0 ? wq : wsel == 1 ? wk : wsel == 2 ? wv : wm;
    dst = wsel == 0 ? oq : wsel == 1 ? okk : wsel == 2 ? ov : om;
  } else if (bid < 128) { t = bid - 64; K = 512; N = 512; src = w1; dst = o1; }
  else                  { t = bid - 128; K = 512; N = 256; src = w2; dst = o2; }
  const int ntn = N >> 6;
  const int tn = t % ntn, tk = t / ntn;
  const int tid = threadIdx.x, ln = tid & 63, lrr = tid >> 6;
  for (int k = 0; k < 64; k += 4)
    ts[k + lrr][ln] = src[(size_t)(tk * 64 + k + lrr) * N + tn * 64 + ln];
  __syncthreads();
  for (int k = 0; k < 64; k += 4)
    dst[(size_t)(tn * 64 + k + lrr) * K + tk * 64 + ln] = f2bf(ts[ln][k + lrr]);
}

// ---------------------------------------------------------------------------
// Fused 4x4 maxpool (NCHW) + layernorm over C -> bf16 rows
// ---------------------------------------------------------------------------
__global__ __launch_bounds__(256) void pool_ln_kernel(
    const float* __restrict__ x, const float* __restrict__ src,
    const float* __restrict__ g, const float* __restrict__ bb,
    u16* __restrict__ qout, u16* __restrict__ sout)
{
  __shared__ float pool[256 * 33];
  __shared__ float redA[8][32];
  __shared__ float redB[8][32];
  __shared__ float stat_m[32];
  __shared__ float stat_r[32];
  const int ph = blockIdx.x, b = blockIdx.y;
  const float* in = blockIdx.z ? src : x;
  u16* out = blockIdx.z ? sout : qout;
  const int tid = threadIdx.x;
  const int pw = tid & 31, cg = tid >> 5;
  for (int kk = 0; kk < 32; ++kk) {
    const int c = cg * 32 + kk;
    const float* base = in + (((size_t)b * 256 + c) * 128 + ph * 4) * 128 + pw * 4;
    float4 v0 = *(const float4*)(base);
    float4 v1 = *(const float4*)(base + 128);
    float4 v2 = *(const float4*)(base + 256);
    float4 v3 = *(const float4*)(base + 384);
    float m = fmaxf(fmaxf(fmaxf(v0.x, v0.y), fmaxf(v0.z, v0.w)),
                    fmaxf(fmaxf(v1.x, v1.y), fmaxf(v1.z, v1.w)));
    m = fmaxf(m, fmaxf(fmaxf(v2.x, v2.y), fmaxf(v2.z, v2.w)));
    m = fmaxf(m, fmaxf(fmaxf(v3.x, v3.y), fmaxf(v3.z, v3.w)));
    pool[c * 33 + pw] = m;
  }
  __syncthreads();
  float s = 0.f, s2 = 0.f;
  for (int i = 0; i < 32; ++i) {
    float v = pool[(cg * 32 + i) * 33 + pw];
    s += v; s2 += v * v;
  }
  redA[cg][pw] = s; redB[cg][pw] = s2;
  __syncthreads();
  if (tid < 32) {
    float ss = 0.f, ss2 = 0.f;
    for (int i = 0; i < 8; ++i) { ss += redA[i][tid]; ss2 += redB[i][tid]; }
    float mean = ss * (1.f / 256.f);
    float var = ss2 * (1.f / 256.f) - mean * mean;
    stat_m[tid] = mean;
    stat_r[tid] = rsqrtf(var + 1e-5f);
  }
  __syncthreads();
  const float gc = g[tid], bc = bb[tid];
  const size_t rowbase = ((size_t)b * 1024 + ph * 32) * 256;
  for (int p = 0; p < 32; ++p) {
    float v = (pool[tid * 33 + p] - stat_m[p]) * stat_r[p] * gc + bc;
    out[rowbase + (size_t)p * 256 + tid] = f2bf(v);
  }
}

// ---------------------------------------------------------------------------
// KV[d][v] + Ksum[d] per (b,h). grid (8 h, 4 b)
// ---------------------------------------------------------------------------
__global__ __launch_bounds__(256) void kv_kernel(
    const float* __restrict__ Kp, const float* __restrict__ Vn,
    float* __restrict__ kvbuf)
{
  __shared__ float kch[128 * 33];
  __shared__ float vch[128 * 33];
  const int h = blockIdx.x, b = blockIdx.y;
  const int tid = threadIdx.x;
  const int d = tid & 31, sl = tid >> 5;
  const int v = tid & 31, dp = tid >> 5;
  float a0 = 0.f, a1 = 0.f, a2 = 0.f, a3 = 0.f, ks = 0.f;
  for (int ch = 0; ch < 8; ++ch) {
    __syncthreads();
    for (int ss = 0; ss < 16; ++ss) {
      const int srow = ch * 128 + ss * 8 + sl;
      const size_t gi = ((size_t)b * 1024 + srow) * 256 + h * 32 + d;
      kch[(ss * 8 + sl) * 33 + d] = Kp[gi];
      vch[(ss * 8 + sl) * 33 + d] = Vn[gi];
    }
    __syncthreads();
    for (int s = 0; s < 128; ++s) {
      const float vv = vch[s * 33 + v];
      a0 += kch[s * 33 + dp] * vv;
      a1 += kch[s * 33 + dp + 8] * vv;
      a2 += kch[s * 33 + dp + 16] * vv;
      a3 += kch[s * 33 + dp + 24] * vv;
    }
    if (tid < 32)
      for (int s = 0; s < 128; ++s) ks += kch[s * 33 + tid];
  }
  float* outp = kvbuf + ((size_t)b * 8 + h) * 1056;
  outp[(dp) * 32 + v]      = a0;
  outp[(dp + 8) * 32 + v]  = a1;
  outp[(dp + 16) * 32 + v] = a2;
  outp[(dp + 24) * 32 + v] = a3;
  if (tid < 32) outp[1024 + tid] = ks;
}

// ---------------------------------------------------------------------------
// msg[l,h,v] = (Qp[l].KV[:,v]) * 1024 / (Qp[l].Ksum + 1e-6) -> bf16
// ---------------------------------------------------------------------------
__global__ __launch_bounds__(256) void msg_kernel(
    const float* __restrict__ Qp, const float* __restrict__ kvbuf,
    u16* __restrict__ msg2)
{
  __shared__ float kv[32 * 33];
  __shared__ float ksum[32];
  __shared__ float qch[8 * 33];
  const int lc = blockIdx.x, h = blockIdx.y, b = blockIdx.z;
  const int tid = threadIdx.x;
  const float* kvp = kvbuf + ((size_t)b * 8 + h) * 1056;
  for (int i = tid; i < 1024; i += 256) kv[(i >> 5) * 33 + (i & 31)] = kvp[i];
  if (tid < 32) ksum[tid] = kvp[1024 + tid];
  const int d = tid & 31, lr = tid >> 5;
  const int v = tid & 31;
  for (int ps = 0; ps < 8; ++ps) {
    __syncthreads();
    const int l = lc * 64 + ps * 8 + lr;
    qch[lr * 33 + d] = Qp[((size_t)b * 1024 + l) * 256 + h * 32 + d];
    __syncthreads();
    float dot = 0.f, zden = 0.f;
    for (int dd = 0; dd < 32; ++dd) {
      const float q = qch[lr * 33 + dd];
      dot  += q * kv[dd * 33 + v];
      zden += q * ksum[dd];
    }
    const float m = dot * (1024.f / (zden + 1e-6f));
    msg2[((size_t)b * 1024 + l) * 256 + h * 32 + v] = f2bf(m);
  }
}

// ---------------------------------------------------------------------------
// Prep: y<4 -> x NCHW fp32 -> xbf NHWC bf16 ; y==4 -> bilinear upsample -> ub
// grid (2 jc, 5 y, 128*nb), block 256
// ---------------------------------------------------------------------------
__global__ __launch_bounds__(256) void prep_kernel(
    const float* __restrict__ x, const u16* __restrict__ merged,
    u16* __restrict__ xbf, u16* __restrict__ ub, int b0)
{
  __shared__ float ts[64][65];
  const int jc = blockIdx.x, y = blockIdx.y, iz = blockIdx.z;
  const int localb = iz >> 7;
  const int b = b0 + localb;
  const int i = iz & 127;
  const int tid = threadIdx.x;
  if (y < 4) {
    const int cc = y, ln = tid & 63, lrr = tid >> 6;
    const float* xp = x + (size_t)b * 256 * 16384;
    for (int k = 0; k < 64; k += 4)
      ts[k + lrr][ln] = xp[((size_t)(cc * 64 + k + lrr) * 128 + i) * 128 + jc * 64 + ln];
    __syncthreads();
    for (int k = 0; k < 64; k += 4) {
      const size_t row = (size_t)localb * 16384 + (size_t)i * 128 + jc * 64 + k + lrr;
      xbf[row * 256 + cc * 64 + ln] = f2bf(ts[ln][k + lrr]);
    }
  } else {
    const float sy = 0.25f * i - 0.375f;
    const float fy = floorf(sy);
    const float wy = sy - fy;
    const int y0 = max(0, min(31, (int)fy));
    const int y1 = max(0, min(31, (int)fy + 1));
    const u16* mb = merged + (size_t)b * 1024 * 256;
    for (int p = 0; p < 64; ++p) {
      const int j = jc * 64 + p;
      const float sx = 0.25f * j - 0.375f;
      const float fx = floorf(sx);
      const float wx = sx - fx;
      const int x0 = max(0, min(31, (int)fx));
      const int x1 = max(0, min(31, (int)fx + 1));
      const u16* r00 = mb + ((size_t)y0 * 32 + x0) * 256;
      const u16* r01 = mb + ((size_t)y0 * 32 + x1) * 256;
      const u16* r10 = mb + ((size_t)y1 * 32 + x0) * 256;
      const u16* r11 = mb + ((size_t)y1 * 32 + x1) * 256;
      const float v = (1.f - wy) * ((1.f - wx) * bf2f(r00[tid]) + wx * bf2f(r01[tid]))
                    +        wy  * ((1.f - wx) * bf2f(r10[tid]) + wx * bf2f(r11[tid]));
      const size_t row = (size_t)localb * 16384 + (size_t)i * 128 + j;
      ub[row * 256 + tid] = f2bf(v);
    }
  }
}

// ---------------------------------------------------------------------------
extern "C" void kernel_launch(void* const* d_in, const int* in_sizes, int n_in,
                              void* d_out, int out_size, void* d_ws, size_t ws_size,
                              hipStream_t stream) {
  (void)in_sizes; (void)n_in; (void)out_size;
  const float* x   = (const float*)d_in[0];
  const float* src = (const float*)d_in[1];
  const float* n1g = (const float*)d_in[2];
  const float* n1b = (const float*)d_in[3];
  const float* w_q = (const float*)d_in[4];
  const float* w_k = (const float*)d_in[5];
  const float* w_v = (const float*)d_in[6];
  const float* w_m = (const float*)d_in[7];
  const float* w1  = (const float*)d_in[8];
  const float* w2  = (const float*)d_in[9];
  const float* n2g = (const float*)d_in[10];
  const float* n2b = (const float*)d_in[11];
  float* out = (float*)d_out;

  char* ws = (char*)d_ws;
  size_t off = 0;
  auto alloc = [&](size_t bytes) -> void* {
    void* p = ws + off;
    off = (off + bytes + 255) & ~(size_t)255;
    return p;
  };
  u16* wqT = (u16*)alloc(256 * 256 * 2);
  u16* wkT = (u16*)alloc(256 * 256 * 2);
  u16* wvT = (u16*)alloc(256 * 256 * 2);
  u16* wmT = (u16*)alloc(256 * 256 * 2);
  u16* w1T = (u16*)alloc(512 * 512 * 2);
  u16* w2T = (u16*)alloc(256 * 512 * 2);
  u16* qbf = (u16*)alloc((size_t)4096 * 256 * 2);
  u16* sbf = (u16*)alloc((size_t)4096 * 256 * 2);
  float* Qp = (float*)alloc((size_t)4096 * 256 * 4);
  float* Kp = (float*)alloc((size_t)4096 * 256 * 4);
  float* Vn = (float*)alloc((size_t)4096 * 256 * 4);
  float* kvb = (float*)alloc((size_t)32 * 1056 * 4);
  u16* msg2   = (u16*)alloc((size_t)4096 * 256 * 2);
  u16* merged = (u16*)alloc((size_t)4096 * 256 * 2);

  size_t remain = (ws_size > off) ? ws_size - off : 0;
  auto need = [](int nb) { return (size_t)nb * 16384 * (256 + 256 + 512) * 2 + 4096; };
  int nb = (remain >= need(4)) ? 4 : (remain >= need(2)) ? 2 : 1;
  u16* xbf = (u16*)alloc((size_t)nb * 16384 * 256 * 2);
  u16* ub  = (u16*)alloc((size_t)nb * 16384 * 256 * 2);
  u16* hid = (u16*)alloc((size_t)nb * 16384 * 512 * 2);

  transpose_w_kernel<<<dim3(160), dim3(256), 0, stream>>>(
      w_q, w_k, w_v, w_m, w1, w2, wqT, wkT, wvT, wmT, w1T, w2T);

  pool_ln_kernel<<<dim3(32, 4, 2), dim3(256), 0, stream>>>(
      x, src, n1g, n1b, qbf, sbf);

  qkv_kernel<<<dim3(32, 2, 3), dim3(256), 0, stream>>>(
      qbf, sbf, wqT, wkT, wvT, Qp, Kp, Vn);

  kv_kernel<<<dim3(8, 4), dim3(256), 0, stream>>>(Kp, Vn, kvb);
  msg_kernel<<<dim3(16, 8, 4), dim3(256), 0, stream>>>(Qp, kvb, msg2);

  merge_kernel<<<dim3(32, 2), dim3(256), 0, stream>>>(msg2, wmT, merged);

  for (int b0 = 0; b0 < 4; b0 += nb) {
    prep_kernel<<<dim3(2, 5, 128 * nb), dim3(256), 0, stream>>>(
        x, merged, xbf, ub, b0);
    mlp1_kernel<<<dim3(2, nb * 128), dim3(256), 0, stream>>>(
        xbf, ub, w1T, hid);
    mlp2_kernel<<<dim3(nb * 128), dim3(256), 0, stream>>>(
        hid, w2T, x, n2g, n2b, out, b0 * 16384);
  }
}